// Round 1
// baseline (378.242 us; speedup 1.0000x reference)
//
#include <hip/hip_runtime.h>
#include <hip/hip_bf16.h>

typedef unsigned short u16;
typedef __bf16 bf16x8 __attribute__((ext_vector_type(8)));
typedef float f32x4 __attribute__((ext_vector_type(4)));

#define BATCH 16
#define C 256
#define NTOK 4096      // H*W
#define CN 1048576     // C*NTOK

__device__ __forceinline__ u16 f2b(float f) {
  __hip_bfloat16 h = __float2bfloat16(f);
  return __builtin_bit_cast(u16, h);
}
__device__ __forceinline__ float b2f(u16 u) {
  unsigned int x = ((unsigned int)u) << 16;
  return __builtin_bit_cast(float, x);
}

// ---------------------------------------------------------------------------
// prep_x: x f32 [B][C][N] -> x_bf16 [B][C][N] and xT_bf16 [B][N][C]
// grid (N/32=128, C/32=8, B), block 256
__global__ __launch_bounds__(256) void prep_x_kernel(
    const float* __restrict__ x, u16* __restrict__ xbf, u16* __restrict__ xT) {
  __shared__ float t[32][33];
  int b = blockIdx.z;
  int c0 = blockIdx.y * 32, n0 = blockIdx.x * 32;
  int tid = threadIdx.x;
  int i = tid >> 3, j4 = (tid & 7) * 4;
  const float* xb = x + (long)b * CN;
  float4 v = *(const float4*)(xb + (long)(c0 + i) * NTOK + n0 + j4);
  ushort4 bv;
  bv.x = f2b(v.x); bv.y = f2b(v.y); bv.z = f2b(v.z); bv.w = f2b(v.w);
  *(ushort4*)(xbf + (long)b * CN + (long)(c0 + i) * NTOK + n0 + j4) = bv;
  t[i][j4 + 0] = v.x; t[i][j4 + 1] = v.y; t[i][j4 + 2] = v.z; t[i][j4 + 3] = v.w;
  __syncthreads();
  ushort4 o;
  o.x = f2b(t[j4 + 0][i]); o.y = f2b(t[j4 + 1][i]);
  o.z = f2b(t[j4 + 2][i]); o.w = f2b(t[j4 + 3][i]);
  *(ushort4*)(xT + (long)b * CN + (long)(n0 + i) * C + c0 + j4) = o;
}

// ---------------------------------------------------------------------------
// prep_w: convert weights to bf16; build WvT (transposed Wv) and conv weights
// reordered to [o][tap][i]. grid 3328 x 256.
__global__ __launch_bounds__(256) void prep_w_kernel(
    const float* __restrict__ qkv_w, const float* __restrict__ proj_w,
    const float* __restrict__ conv_w, u16* __restrict__ Wq, u16* __restrict__ Wk,
    u16* __restrict__ WvT, u16* __restrict__ Pw, u16* __restrict__ cw) {
  int idx = blockIdx.x * 256 + threadIdx.x;
  if (idx < 65536) {
    Wq[idx] = f2b(qkv_w[idx]);
  } else if (idx < 131072) {
    int e = idx - 65536;
    Wk[e] = f2b(qkv_w[65536 + e]);
  } else if (idx < 196608) {
    int e = idx - 131072;
    int i = e >> 8, d = e & 255;
    WvT[e] = f2b(qkv_w[131072 + d * 256 + i]);  // Wv row d = qkv_w row 512+d
  } else if (idx < 262144) {
    int e = idx - 196608;
    Pw[e] = f2b(proj_w[e]);
  } else if (idx < 851968) {
    int e = idx - 262144;
    int o = e / 2304;
    int rem = e - o * 2304;
    int tap = rem >> 8, i = rem & 255;
    cw[e] = f2b(conv_w[o * 2304 + i * 9 + tap]);
  }
}

// ---------------------------------------------------------------------------
// rowsum: r[b][c] = sum_n x[b][c][n]  (for qkv bias terms; exact f32 path)
__global__ __launch_bounds__(256) void rowsum_kernel(const float* __restrict__ x,
                                                     float* __restrict__ r) {
  int row = blockIdx.x;  // b*C + c
  const float* p = x + (long)row * NTOK;
  float s = 0.f;
  for (int i = threadIdx.x; i < NTOK; i += 256) s += p[i];
  __shared__ float red[256];
  int t = threadIdx.x;
  red[t] = s; __syncthreads();
  for (int st = 128; st > 0; st >>= 1) {
    if (t < st) red[t] += red[t + st];
    __syncthreads();
  }
  if (t == 0) r[row] = red[0];
}

// bias_uw: u[b][d] = sum_i Wk[d,i]*r[b,i] ; w[b][c] = sum_i Wq[c,i]*r[b,i]
__global__ __launch_bounds__(512) void bias_uw_kernel(
    const float* __restrict__ qkv_w, const float* __restrict__ r,
    float* __restrict__ u, float* __restrict__ w) {
  int b = blockIdx.x, t = threadIdx.x;
  const float* rb = r + b * C;
  if (t < 256) {
    float s = 0.f;
    for (int i = 0; i < C; ++i) s += qkv_w[(256 + t) * 256 + i] * rb[i];
    u[b * C + t] = s;
  } else {
    int c = t - 256;
    float s = 0.f;
    for (int i = 0; i < C; ++i) s += qkv_w[c * 256 + i] * rb[i];
    w[b * C + c] = s;
  }
}

// ---------------------------------------------------------------------------
// Generic bf16 MFMA GEMM: C[M][N] = A[M][K] * B[N][K]^T  (both K-contiguous)
// 128x128 tile, BK=32, 4 waves, reg-staged LDS.
// EPI 1: store bf16. EPI 2: S epilogue (scale + qkv-bias terms), f32.
// EPI 3: out += acc + cbias[col]  (f32 RMW)
template <int EPI>
__global__ __launch_bounds__(256) void gemm_bt_kernel(
    const u16* __restrict__ A, const u16* __restrict__ B, void* __restrict__ Cv,
    int K, int lda, int ldb, int ldc, int tilesN, long sA, long sB, long sC,
    float scale, const float* __restrict__ e1, const float* __restrict__ e2,
    const float* __restrict__ e3, const float* __restrict__ e4, int e34stride) {
  int b = blockIdx.y;
  A += (long)b * sA;
  B += (long)b * sB;
  int ty = blockIdx.x / tilesN, tx = blockIdx.x % tilesN;
  int row0 = ty * 128, col0 = tx * 128;

  __shared__ u16 ldsA[128 * 32];
  __shared__ u16 ldsB[128 * 32];

  int tid = threadIdx.x;
  int lane = tid & 63, wv = tid >> 6;
  int wm = wv >> 1, wn = wv & 1;
  int fr = lane & 15, kq = lane >> 4;

  f32x4 acc[4][4] = {};

  int srow = tid >> 1;
  int skb = (tid & 1) * 16;
  const u16* pA = A + (long)(row0 + srow) * lda + skb;
  const u16* pB = B + (long)(col0 + srow) * ldb + skb;
  u16* wAp = &ldsA[srow * 32 + skb];
  u16* wBp = &ldsB[srow * 32 + skb];

  for (int k0 = 0; k0 < K; k0 += 32) {
    uint4 a0 = *(const uint4*)(pA + k0);
    uint4 a1 = *(const uint4*)(pA + k0 + 8);
    uint4 b0 = *(const uint4*)(pB + k0);
    uint4 b1 = *(const uint4*)(pB + k0 + 8);
    __syncthreads();
    *(uint4*)wAp = a0; *(uint4*)(wAp + 8) = a1;
    *(uint4*)wBp = b0; *(uint4*)(wBp + 8) = b1;
    __syncthreads();
    bf16x8 af[4], bfr[4];
#pragma unroll
    for (int m = 0; m < 4; ++m)
      af[m] = *(const bf16x8*)&ldsA[(wm * 64 + m * 16 + fr) * 32 + kq * 8];
#pragma unroll
    for (int n = 0; n < 4; ++n)
      bfr[n] = *(const bf16x8*)&ldsB[(wn * 64 + n * 16 + fr) * 32 + kq * 8];
#pragma unroll
    for (int m = 0; m < 4; ++m)
#pragma unroll
      for (int n = 0; n < 4; ++n)
        acc[m][n] = __builtin_amdgcn_mfma_f32_16x16x32_bf16(af[m], bfr[n], acc[m][n], 0, 0, 0);
  }

  if (EPI == 1) {
    __hip_bfloat16* Cb = (__hip_bfloat16*)Cv + (long)b * sC;
#pragma unroll
    for (int m = 0; m < 4; ++m)
#pragma unroll
      for (int n = 0; n < 4; ++n)
#pragma unroll
        for (int r = 0; r < 4; ++r) {
          int gr = row0 + wm * 64 + m * 16 + kq * 4 + r;
          int gc = col0 + wn * 64 + n * 16 + fr;
          Cb[(long)gr * ldc + gc] = __float2bfloat16(acc[m][n][r]);
        }
  } else if (EPI == 2) {
    float* Cb = (float*)Cv + (long)b * sC;
    const float* ub = e3 + (long)b * e34stride;
    const float* wb = e4 + (long)b * e34stride;
#pragma unroll
    for (int m = 0; m < 4; ++m)
#pragma unroll
      for (int n = 0; n < 4; ++n)
#pragma unroll
        for (int r = 0; r < 4; ++r) {
          int gr = row0 + wm * 64 + m * 16 + kq * 4 + r;
          int gc = col0 + wn * 64 + n * 16 + fr;
          float v = acc[m][n][r] + e1[gr] * ub[gc] + e2[gc] * wb[gr] +
                    4096.0f * e1[gr] * e2[gc];
          Cb[(long)gr * ldc + gc] = v * scale;
        }
  } else if (EPI == 3) {
    float* Cb = (float*)Cv + (long)b * sC;
    const float* cbb = e1 + (long)b * e34stride;
#pragma unroll
    for (int m = 0; m < 4; ++m)
#pragma unroll
      for (int n = 0; n < 4; ++n)
#pragma unroll
        for (int r = 0; r < 4; ++r) {
          int gr = row0 + wm * 64 + m * 16 + kq * 4 + r;
          int gc = col0 + wn * 64 + n * 16 + fr;
          long idx = (long)gr * ldc + gc;
          Cb[idx] = Cb[idx] + acc[m][n][r] + cbb[gc];
        }
  }
}

// ---------------------------------------------------------------------------
// softmax over rows of S (B*C rows of length C) -> attn bf16 row-major
__global__ __launch_bounds__(256) void softmax_kernel(const float* __restrict__ S,
                                                      u16* __restrict__ attn) {
  int row = blockIdx.x;
  int t = threadIdx.x;
  float v = S[(long)row * C + t];
  __shared__ float red[256];
  red[t] = v; __syncthreads();
  for (int st = 128; st > 0; st >>= 1) {
    if (t < st) red[t] = fmaxf(red[t], red[t + st]);
    __syncthreads();
  }
  float mx = red[0];
  __syncthreads();
  float e = __expf(v - mx);
  red[t] = e; __syncthreads();
  for (int st = 128; st > 0; st >>= 1) {
    if (t < st) red[t] += red[t + st];
    __syncthreads();
  }
  float inv = 1.0f / red[0];
  attn[(long)row * C + t] = f2b(e * inv);
}

// transpose attn [256][256] per batch (bf16). grid (8,8,B), block 256
__global__ __launch_bounds__(256) void transpose256_kernel(
    const u16* __restrict__ in, u16* __restrict__ out) {
  __shared__ u16 t[32][36];
  int b = blockIdx.z;
  int bx = blockIdx.x, by = blockIdx.y;
  const u16* ib = in + (long)b * 65536;
  u16* ob = out + (long)b * 65536;
  int tid = threadIdx.x;
  int i = tid >> 3, j4 = (tid & 7) * 4;
  ushort4 v = *(const ushort4*)(ib + (by * 32 + i) * 256 + bx * 32 + j4);
  t[i][j4 + 0] = v.x; t[i][j4 + 1] = v.y; t[i][j4 + 2] = v.z; t[i][j4 + 3] = v.w;
  __syncthreads();
  ushort4 o;
  o.x = t[j4 + 0][i]; o.y = t[j4 + 1][i]; o.z = t[j4 + 2][i]; o.w = t[j4 + 3][i];
  *(ushort4*)(ob + (bx * 32 + i) * 256 + by * 32 + j4) = o;
}

// cbias[b][j] = proj_b[j] + sum_d M[b][j][d]*qkv_b[512+d]
__global__ __launch_bounds__(256) void cbias_kernel(const u16* __restrict__ M,
                                                    const float* __restrict__ qkv_b,
                                                    const float* __restrict__ proj_b,
                                                    float* __restrict__ cb) {
  int b = blockIdx.x, j = threadIdx.x;
  const u16* m = M + (long)b * 65536 + (long)j * 256;
  float s = 0.f;
  for (int d = 0; d < C; ++d) s += b2f(m[d]) * qkv_b[512 + d];
  cb[b * C + j] = proj_b[j] + s;
}

// ---------------------------------------------------------------------------
// conv 3x3 as implicit GEMM: out[b][o][n] = sum_{tap,i} cw[o][tap][i]*xT[n+shift][i]
// tile 128(o) x 128(n), K = 9 taps x 256. grid (64, B), block 256.
__global__ __launch_bounds__(256) void conv_kernel(
    const u16* __restrict__ xT, const u16* __restrict__ cw,
    const float* __restrict__ conv_b, float* __restrict__ out) {
  int b = blockIdx.y;
  int to = blockIdx.x >> 5;  // 0..1
  int tn = blockIdx.x & 31;  // 0..31
  int row0 = to * 128, col0 = tn * 128;
  const u16* xTb = xT + (long)b * CN;

  __shared__ u16 ldsA[128 * 32];
  __shared__ u16 ldsB[128 * 32];

  int tid = threadIdx.x;
  int lane = tid & 63, wv = tid >> 6;
  int wm = wv >> 1, wn = wv & 1;
  int fr = lane & 15, kq = lane >> 4;
  f32x4 acc[4][4] = {};

  int srow = tid >> 1;
  int skb = (tid & 1) * 16;
  const u16* pA = cw + (long)(row0 + srow) * 2304 + skb;
  u16* wAp = &ldsA[srow * 32 + skb];
  u16* wBp = &ldsB[srow * 32 + skb];
  int n = col0 + srow;
  int h = n >> 6, w_ = n & 63;

  for (int tap = 0; tap < 9; ++tap) {
    int dh = tap / 3 - 1, dw = tap % 3 - 1;
    bool valid = ((unsigned)(h + dh) < 64u) && ((unsigned)(w_ + dw) < 64u);
    const u16* pB = xTb + (long)(n + dh * 64 + dw) * C + skb;
    for (int i0 = 0; i0 < 256; i0 += 32) {
      uint4 a0 = *(const uint4*)(pA + tap * 256 + i0);
      uint4 a1 = *(const uint4*)(pA + tap * 256 + i0 + 8);
      uint4 b0 = {}, b1 = {};
      if (valid) {
        b0 = *(const uint4*)(pB + i0);
        b1 = *(const uint4*)(pB + i0 + 8);
      }
      __syncthreads();
      *(uint4*)wAp = a0; *(uint4*)(wAp + 8) = a1;
      *(uint4*)wBp = b0; *(uint4*)(wBp + 8) = b1;
      __syncthreads();
      bf16x8 af[4], bfr[4];
#pragma unroll
      for (int m = 0; m < 4; ++m)
        af[m] = *(const bf16x8*)&ldsA[(wm * 64 + m * 16 + fr) * 32 + kq * 8];
#pragma unroll
      for (int nn = 0; nn < 4; ++nn)
        bfr[nn] = *(const bf16x8*)&ldsB[(wn * 64 + nn * 16 + fr) * 32 + kq * 8];
#pragma unroll
      for (int m = 0; m < 4; ++m)
#pragma unroll
        for (int nn = 0; nn < 4; ++nn)
          acc[m][nn] = __builtin_amdgcn_mfma_f32_16x16x32_bf16(af[m], bfr[nn], acc[m][nn], 0, 0, 0);
    }
  }

  float* ob = out + (long)b * CN;
#pragma unroll
  for (int m = 0; m < 4; ++m)
#pragma unroll
    for (int nn = 0; nn < 4; ++nn)
#pragma unroll
      for (int r = 0; r < 4; ++r) {
        int go = row0 + wm * 64 + m * 16 + kq * 4 + r;
        int gn = col0 + wn * 64 + nn * 16 + fr;
        ob[(long)go * NTOK + gn] = acc[m][nn][r] + conv_b[go];
      }
}

// ---------------------------------------------------------------------------
extern "C" void kernel_launch(void* const* d_in, const int* in_sizes, int n_in,
                              void* d_out, int out_size, void* d_ws, size_t ws_size,
                              hipStream_t stream) {
  const float* x = (const float*)d_in[0];
  const float* qkv_w = (const float*)d_in[1];
  const float* qkv_b = (const float*)d_in[2];
  const float* proj_w = (const float*)d_in[3];
  const float* proj_b = (const float*)d_in[4];
  const float* conv_w = (const float*)d_in[5];
  const float* conv_b = (const float*)d_in[6];
  float* out = (float*)d_out;
  char* ws = (char*)d_ws;

  u16* xbf = (u16*)(ws);                       // 33554432 B
  u16* xT = (u16*)(ws + 33554432);             // 33554432 B
  u16* Gbf = (u16*)(ws + 67108864);            // 2097152 B
  u16* T1bf = (u16*)(ws + 69206016);           // 2097152 B
  float* Sf = (float*)(ws + 71303168);         // 4194304 B
  u16* attnbf = (u16*)(ws + 75497472);         // 2097152 B
  u16* attnTbf = (u16*)(ws + 77594624);        // 2097152 B
  u16* Mbf = (u16*)(ws + 79691776);            // 2097152 B
  u16* W2bf = (u16*)(ws + 81788928);           // 2097152 B
  u16* Wq = (u16*)(ws + 83886080);             // 131072 B
  u16* Wk = (u16*)(ws + 84017152);             // 131072 B
  u16* WvT = (u16*)(ws + 84148224);            // 131072 B
  u16* Pw = (u16*)(ws + 84279296);             // 131072 B
  u16* cw = (u16*)(ws + 84410368);             // 1179648 B
  float* rws = (float*)(ws + 85590016);        // 16384 B
  float* uws = (float*)(ws + 85606400);        // 16384 B
  float* wws = (float*)(ws + 85622784);        // 16384 B
  float* cb = (float*)(ws + 85639168);         // 16384 B

  prep_x_kernel<<<dim3(128, 8, BATCH), 256, 0, stream>>>(x, xbf, xT);
  prep_w_kernel<<<3328, 256, 0, stream>>>(qkv_w, proj_w, conv_w, Wq, Wk, WvT, Pw, cw);
  rowsum_kernel<<<BATCH * C, 256, 0, stream>>>(x, rws);
  bias_uw_kernel<<<BATCH, 512, 0, stream>>>(qkv_w, rws, uws, wws);

  // G = X * X^T   (per batch, 256x256, K=4096)
  gemm_bt_kernel<1><<<dim3(4, BATCH), 256, 0, stream>>>(
      xbf, xbf, Gbf, 4096, 4096, 4096, 256, 2, CN, CN, 65536,
      0.f, nullptr, nullptr, nullptr, nullptr, 0);
  // T1 = Wq * G  (G symmetric -> A@B^T form)
  gemm_bt_kernel<1><<<dim3(4, BATCH), 256, 0, stream>>>(
      Wq, Gbf, T1bf, 256, 256, 256, 256, 2, 0, 65536, 65536,
      0.f, nullptr, nullptr, nullptr, nullptr, 0);
  // S = (T1 * Wk^T + bias terms) * scale
  gemm_bt_kernel<2><<<dim3(4, BATCH), 256, 0, stream>>>(
      T1bf, Wk, Sf, 256, 256, 256, 256, 2, 65536, 0, 65536,
      0.0625f, qkv_b, qkv_b + 256, uws, wws, 256);

  softmax_kernel<<<BATCH * C, 256, 0, stream>>>(Sf, attnbf);
  transpose256_kernel<<<dim3(8, 8, BATCH), 256, 0, stream>>>(attnbf, attnTbf);

  // M = Pw * attn   (B operand = attn^T)
  gemm_bt_kernel<1><<<dim3(4, BATCH), 256, 0, stream>>>(
      Pw, attnTbf, Mbf, 256, 256, 256, 256, 2, 0, 65536, 65536,
      0.f, nullptr, nullptr, nullptr, nullptr, 0);
  cbias_kernel<<<BATCH, 256, 0, stream>>>(Mbf, qkv_b, proj_b, cb);
  // W2 = M * Wv     (B operand = WvT)
  gemm_bt_kernel<1><<<dim3(4, BATCH), 256, 0, stream>>>(
      Mbf, WvT, W2bf, 256, 256, 256, 256, 2, 65536, 0, 65536,
      0.f, nullptr, nullptr, nullptr, nullptr, 0);

  // conv writes out first
  conv_kernel<<<dim3(64, BATCH), 256, 0, stream>>>(xT, cw, conv_b, out);
  // out[n*C+j] += (xT * W2^T)[n][j] + cbias[j]
  gemm_bt_kernel<3><<<dim3(64, BATCH), 256, 0, stream>>>(
      xT, W2bf, out, 256, 256, 256, 256, 2, CN, 65536, CN,
      0.f, cb, nullptr, nullptr, nullptr, 256);
}

// Round 2
// 250.030 us; speedup vs baseline: 1.5128x; 1.5128x over previous
//
#include <hip/hip_runtime.h>
#include <hip/hip_bf16.h>

typedef unsigned short u16;
typedef __bf16 bf16x8 __attribute__((ext_vector_type(8)));
typedef float f32x4 __attribute__((ext_vector_type(4)));

#define BATCH 16
#define C 256
#define NTOK 4096      // H*W
#define CN 1048576     // C*NTOK

__device__ __forceinline__ u16 f2b(float f) {
  __hip_bfloat16 h = __float2bfloat16(f);
  return __builtin_bit_cast(u16, h);
}
__device__ __forceinline__ float b2f(u16 u) {
  unsigned int x = ((unsigned int)u) << 16;
  return __builtin_bit_cast(float, x);
}

// async global->LDS, 16B per lane. LDS dest must be wave-uniform base
// (HW adds lane*16); global src is per-lane.
__device__ __forceinline__ void glds16(const u16* g, u16* l) {
  __builtin_amdgcn_global_load_lds(
      (const __attribute__((address_space(1))) unsigned int*)(g),
      (__attribute__((address_space(3))) unsigned int*)(l), 16, 0, 0);
}

// ---------------------------------------------------------------------------
// prep_x: x f32 [B][C][N] -> xbf [B][C][N], xT [B][N][C]; row partial sums
// atomically into rws (rws zeroed by prep_w, launched before).
// grid (128, 8, B), block 256
__global__ __launch_bounds__(256) void prep_x_kernel(
    const float* __restrict__ x, u16* __restrict__ xbf, u16* __restrict__ xT,
    float* __restrict__ rws) {
  __shared__ float t[32][33];
  int b = blockIdx.z;
  int c0 = blockIdx.y * 32, n0 = blockIdx.x * 32;
  int tid = threadIdx.x;
  int i = tid >> 3, j4 = (tid & 7) * 4;
  const float* xb = x + (long)b * CN;
  float4 v = *(const float4*)(xb + (long)(c0 + i) * NTOK + n0 + j4);
  ushort4 bv;
  bv.x = f2b(v.x); bv.y = f2b(v.y); bv.z = f2b(v.z); bv.w = f2b(v.w);
  *(ushort4*)(xbf + (long)b * CN + (long)(c0 + i) * NTOK + n0 + j4) = bv;
  t[i][j4 + 0] = v.x; t[i][j4 + 1] = v.y; t[i][j4 + 2] = v.z; t[i][j4 + 3] = v.w;
  __syncthreads();
  ushort4 o;
  o.x = f2b(t[j4 + 0][i]); o.y = f2b(t[j4 + 1][i]);
  o.z = f2b(t[j4 + 2][i]); o.w = f2b(t[j4 + 3][i]);
  *(ushort4*)(xT + (long)b * CN + (long)(n0 + i) * C + c0 + j4) = o;
  if (tid < 32) {
    float s = 0.f;
#pragma unroll
    for (int j = 0; j < 32; ++j) s += t[tid][j];
    atomicAdd(&rws[b * C + c0 + tid], s);
  }
}

// ---------------------------------------------------------------------------
// prep_w: bf16-convert weights; WvT transposed; conv w reordered [o][tap][i];
// also zeroes rws and zbuf. grid 3328 x 256.
__global__ __launch_bounds__(256) void prep_w_kernel(
    const float* __restrict__ qkv_w, const float* __restrict__ proj_w,
    const float* __restrict__ conv_w, u16* __restrict__ Wq, u16* __restrict__ Wk,
    u16* __restrict__ WvT, u16* __restrict__ Pw, u16* __restrict__ cw,
    float* __restrict__ rws, u16* __restrict__ zbuf) {
  int idx = blockIdx.x * 256 + threadIdx.x;
  if (idx < 4096) rws[idx] = 0.f;
  if (idx < 256) zbuf[idx] = 0;
  if (idx < 65536) {
    Wq[idx] = f2b(qkv_w[idx]);
  } else if (idx < 131072) {
    int e = idx - 65536;
    Wk[e] = f2b(qkv_w[65536 + e]);
  } else if (idx < 196608) {
    int e = idx - 131072;
    int i = e >> 8, d = e & 255;
    WvT[e] = f2b(qkv_w[131072 + d * 256 + i]);
  } else if (idx < 262144) {
    int e = idx - 196608;
    Pw[e] = f2b(proj_w[e]);
  } else if (idx < 851968) {
    int e = idx - 262144;
    int o = e / 2304;
    int rem = e - o * 2304;
    int tap = rem >> 8, i = rem & 255;
    cw[e] = f2b(conv_w[o * 2304 + i * 9 + tap]);
  }
}

// bias_uw: u[b][d] = Wk[d,:]*r[b,:] ; w[b][c] = Wq[c,:]*r[b,:]
__global__ __launch_bounds__(512) void bias_uw_kernel(
    const float* __restrict__ qkv_w, const float* __restrict__ r,
    float* __restrict__ u, float* __restrict__ w) {
  int b = blockIdx.x, t = threadIdx.x;
  const float* rb = r + b * C;
  if (t < 256) {
    float s = 0.f;
    for (int i = 0; i < C; ++i) s += qkv_w[(256 + t) * 256 + i] * rb[i];
    u[b * C + t] = s;
  } else {
    int c = t - 256;
    float s = 0.f;
    for (int i = 0; i < C; ++i) s += qkv_w[c * 256 + i] * rb[i];
    w[b * C + c] = s;
  }
}

// ---------------------------------------------------------------------------
// Generic GEMM C = A*B^T (both K-contiguous), 128x128 tile, BK=32, 4 waves,
// global_load_lds staging + slot-XOR swizzle, double-buffered.
// grid (tilesM*tilesN, ksplit, batch)
// EPI 0: f32 partial store at (b*gridDim.y+ks)*sC. EPI 1: bf16. EPI 2: S-epi.
template <int EPI>
__global__ __launch_bounds__(256, 2) void gemm_glds_kernel(
    const u16* __restrict__ A, const u16* __restrict__ B, void* __restrict__ Cv,
    int K, int lda, int ldb, int ldc, int tilesN, long sA, long sB, long sC,
    float scale, const float* __restrict__ e1, const float* __restrict__ e2,
    const float* __restrict__ e3, const float* __restrict__ e4, int e34stride) {
  int b = blockIdx.z, ks = blockIdx.y;
  A += (long)b * sA + (long)ks * K;
  B += (long)b * sB + (long)ks * K;
  int ty = blockIdx.x / tilesN, tx = blockIdx.x % tilesN;
  int row0 = ty * 128, col0 = tx * 128;

  __shared__ u16 lA[2][4096];
  __shared__ u16 lB[2][4096];

  int tid = threadIdx.x;
  int lane = tid & 63, wv = tid >> 6;
  int wm = wv >> 1, wn = wv & 1;
  int fr = lane & 15, kq = lane >> 4;
  int kqs = kq ^ ((fr >> 1) & 3);

  // staging chunks: c0 = wv*128+lane, c1 = c0+64 (16B each)
  int c0 = wv * 128 + lane, c1 = c0 + 64;
  int r0s = c0 >> 2, r1s = c1 >> 2;
  int ls0 = (c0 & 3) ^ ((r0s >> 1) & 3);
  int ls1 = (c1 & 3) ^ ((r1s >> 1) & 3);
  const u16* pA0 = A + (long)(row0 + r0s) * lda + ls0 * 8;
  const u16* pA1 = A + (long)(row0 + r1s) * lda + ls1 * 8;
  const u16* pB0 = B + (long)(col0 + r0s) * ldb + ls0 * 8;
  const u16* pB1 = B + (long)(col0 + r1s) * ldb + ls1 * 8;
  int dst0 = wv * 1024, dst1 = wv * 1024 + 512;

  f32x4 acc[4][4] = {};

  auto STAGE = [&](int buf, int t) {
    int k0 = t << 5;
    glds16(pA0 + k0, &lA[buf][dst0]);
    glds16(pA1 + k0, &lA[buf][dst1]);
    glds16(pB0 + k0, &lB[buf][dst0]);
    glds16(pB1 + k0, &lB[buf][dst1]);
  };
  auto COMPUTE = [&](int buf) {
    bf16x8 af[4], bfr[4];
#pragma unroll
    for (int m = 0; m < 4; ++m)
      af[m] = *(const bf16x8*)&lA[buf][(wm * 64 + m * 16 + fr) * 32 + kqs * 8];
#pragma unroll
    for (int n = 0; n < 4; ++n)
      bfr[n] = *(const bf16x8*)&lB[buf][(wn * 64 + n * 16 + fr) * 32 + kqs * 8];
#pragma unroll
    for (int m = 0; m < 4; ++m)
#pragma unroll
      for (int n = 0; n < 4; ++n)
        acc[m][n] = __builtin_amdgcn_mfma_f32_16x16x32_bf16(af[m], bfr[n], acc[m][n], 0, 0, 0);
  };

  int nk = K >> 5, cur = 0;
  STAGE(0, 0);
  __syncthreads();
  for (int t = 0; t < nk; ++t) {
    if (t + 1 < nk) STAGE(cur ^ 1, t + 1);
    COMPUTE(cur);
    __syncthreads();
    cur ^= 1;
  }

  if (EPI == 0) {
    float* Cb = (float*)Cv + ((long)b * gridDim.y + ks) * sC;
#pragma unroll
    for (int m = 0; m < 4; ++m)
#pragma unroll
      for (int n = 0; n < 4; ++n)
#pragma unroll
        for (int r = 0; r < 4; ++r) {
          int gr = row0 + wm * 64 + m * 16 + kq * 4 + r;
          int gc = col0 + wn * 64 + n * 16 + fr;
          Cb[(long)gr * ldc + gc] = acc[m][n][r];
        }
  } else if (EPI == 1) {
    __hip_bfloat16* Cb = (__hip_bfloat16*)Cv + (long)b * sC;
#pragma unroll
    for (int m = 0; m < 4; ++m)
#pragma unroll
      for (int n = 0; n < 4; ++n)
#pragma unroll
        for (int r = 0; r < 4; ++r) {
          int gr = row0 + wm * 64 + m * 16 + kq * 4 + r;
          int gc = col0 + wn * 64 + n * 16 + fr;
          Cb[(long)gr * ldc + gc] = __float2bfloat16(acc[m][n][r]);
        }
  } else if (EPI == 2) {
    float* Cb = (float*)Cv + (long)b * sC;
    const float* ub = e3 + (long)b * e34stride;
    const float* wb = e4 + (long)b * e34stride;
#pragma unroll
    for (int m = 0; m < 4; ++m)
#pragma unroll
      for (int n = 0; n < 4; ++n)
#pragma unroll
        for (int r = 0; r < 4; ++r) {
          int gr = row0 + wm * 64 + m * 16 + kq * 4 + r;
          int gc = col0 + wn * 64 + n * 16 + fr;
          float v = acc[m][n][r] + e1[gr] * ub[gc] + e2[gc] * wb[gr] +
                    4096.0f * e1[gr] * e2[gc];
          Cb[(long)gr * ldc + gc] = v * scale;
        }
  }
}

// reduce 4 f32 split-K partials -> Gbf bf16. grid (64, B), block 256
__global__ __launch_bounds__(256) void reduceG_kernel(
    const float* __restrict__ Gp, u16* __restrict__ G) {
  int b = blockIdx.y;
  int e = blockIdx.x * 1024 + threadIdx.x * 4;
  const float* base = Gp + (long)b * 262144;
  float4 s = *(const float4*)(base + e);
#pragma unroll
  for (int sl = 1; sl < 4; ++sl) {
    float4 v = *(const float4*)(base + sl * 65536 + e);
    s.x += v.x; s.y += v.y; s.z += v.z; s.w += v.w;
  }
  ushort4 o;
  o.x = f2b(s.x); o.y = f2b(s.y); o.z = f2b(s.z); o.w = f2b(s.w);
  *(ushort4*)(G + (long)b * 65536 + e) = o;
}

// ---------------------------------------------------------------------------
// softmax over rows of S -> attn^T bf16 (attnT[d][c] = attn[c][d])
__global__ __launch_bounds__(256) void softmax_kernel(const float* __restrict__ S,
                                                      u16* __restrict__ attnT) {
  int row = blockIdx.x;
  int t = threadIdx.x;
  float v = S[(long)row * C + t];
  __shared__ float red[256];
  red[t] = v; __syncthreads();
  for (int st = 128; st > 0; st >>= 1) {
    if (t < st) red[t] = fmaxf(red[t], red[t + st]);
    __syncthreads();
  }
  float mx = red[0];
  __syncthreads();
  float e = __expf(v - mx);
  red[t] = e; __syncthreads();
  for (int st = 128; st > 0; st >>= 1) {
    if (t < st) red[t] += red[t + st];
    __syncthreads();
  }
  float inv = 1.0f / red[0];
  int b = row >> 8, c = row & 255;
  attnT[(long)b * 65536 + t * 256 + c] = f2b(e * inv);
}

// cbias[b][j] = proj_b[j] + sum_d M[b][j][d]*qkv_b[512+d]
__global__ __launch_bounds__(256) void cbias_kernel(const u16* __restrict__ M,
                                                    const float* __restrict__ qkv_b,
                                                    const float* __restrict__ proj_b,
                                                    float* __restrict__ cb) {
  int b = blockIdx.x, j = threadIdx.x;
  const u16* m = M + (long)b * 65536 + (long)j * 256;
  float s = 0.f;
  for (int d = 0; d < C; ++d) s += b2f(m[d]) * qkv_b[512 + d];
  cb[b * C + j] = proj_b[j] + s;
}

// ---------------------------------------------------------------------------
// Fused conv3x3 implicit-GEMM + attention-output GEMM.
// conv tile [o0:o0+128][n0:n0+128] and attn tile rows n'=o*16+(n0>>8),
// cols j=(n0&255)+c cover the SAME output bytes with identical fragment
// indexing. 72 conv K-steps + 8 attn K-steps; single store.
__global__ __launch_bounds__(256, 2) void convattn_kernel(
    const u16* __restrict__ xT, const u16* __restrict__ cw,
    const u16* __restrict__ W2, const u16* __restrict__ zbuf,
    const float* __restrict__ conv_b, const float* __restrict__ cb,
    float* __restrict__ out) {
  int b = blockIdx.y;
  int to = blockIdx.x >> 5, tn = blockIdx.x & 31;
  int row0 = to * 128, col0 = tn * 128;
  const u16* xTb = xT + (long)b * CN;
  const u16* W2b = W2 + (long)b * 65536;

  __shared__ u16 lA[2][4096];
  __shared__ u16 lB[2][4096];

  int tid = threadIdx.x;
  int lane = tid & 63, wv = tid >> 6;
  int wm = wv >> 1, wn = wv & 1;
  int fr = lane & 15, kq = lane >> 4;
  int kqs = kq ^ ((fr >> 1) & 3);

  int c0 = wv * 128 + lane, c1 = c0 + 64;
  int r0s = c0 >> 2, r1s = c1 >> 2;
  int ls0 = (c0 & 3) ^ ((r0s >> 1) & 3);
  int ls1 = (c1 & 3) ^ ((r1s >> 1) & 3);
  int dst0 = wv * 1024, dst1 = wv * 1024 + 512;

  // conv A (weights), conv B (tokens)
  const u16* pA0 = cw + (long)(row0 + r0s) * 2304 + ls0 * 8;
  const u16* pA1 = cw + (long)(row0 + r1s) * 2304 + ls1 * 8;
  int t0 = col0 + r0s, t1 = col0 + r1s;
  int h0 = t0 >> 6, w0 = t0 & 63, h1 = t1 >> 6, w1 = t1 & 63;
  const u16* pB0 = xTb + (long)t0 * 256 + ls0 * 8;
  const u16* pB1 = xTb + (long)t1 * 256 + ls1 * 8;
  // attn A (gathered xT rows, stride-16 tokens), attn B (W2 rows)
  int nb = col0 >> 8, jb = col0 & 255;
  const u16* qA0 = xTb + (long)((row0 + r0s) * 16 + nb) * 256 + ls0 * 8;
  const u16* qA1 = xTb + (long)((row0 + r1s) * 16 + nb) * 256 + ls1 * 8;
  const u16* qB0 = W2b + (long)(jb + r0s) * 256 + ls0 * 8;
  const u16* qB1 = W2b + (long)(jb + r1s) * 256 + ls1 * 8;

  f32x4 accC[4][4] = {};
  f32x4 accY[4][4] = {};

  auto STAGE_CONV = [&](int buf, int t) {
    int tap = t >> 3, i0 = (t & 7) << 5;
    int dh = tap / 3 - 1, dw = tap % 3 - 1;
    long dt = (long)(dh * 64 + dw) * 256 + i0;
    glds16(pA0 + tap * 256 + i0, &lA[buf][dst0]);
    glds16(pA1 + tap * 256 + i0, &lA[buf][dst1]);
    bool v0 = ((unsigned)(h0 + dh) < 64u) && ((unsigned)(w0 + dw) < 64u);
    bool v1 = ((unsigned)(h1 + dh) < 64u) && ((unsigned)(w1 + dw) < 64u);
    const u16* s0 = v0 ? pB0 + dt : zbuf + ls0 * 8;
    const u16* s1 = v1 ? pB1 + dt : zbuf + ls1 * 8;
    glds16(s0, &lB[buf][dst0]);
    glds16(s1, &lB[buf][dst1]);
  };
  auto STAGE_ATTN = [&](int buf, int t) {
    int k0 = t << 5;
    glds16(qA0 + k0, &lA[buf][dst0]);
    glds16(qA1 + k0, &lA[buf][dst1]);
    glds16(qB0 + k0, &lB[buf][dst0]);
    glds16(qB1 + k0, &lB[buf][dst1]);
  };
  auto COMPUTE = [&](int buf, f32x4 (&acc)[4][4]) {
    bf16x8 af[4], bfr[4];
#pragma unroll
    for (int m = 0; m < 4; ++m)
      af[m] = *(const bf16x8*)&lA[buf][(wm * 64 + m * 16 + fr) * 32 + kqs * 8];
#pragma unroll
    for (int n = 0; n < 4; ++n)
      bfr[n] = *(const bf16x8*)&lB[buf][(wn * 64 + n * 16 + fr) * 32 + kqs * 8];
#pragma unroll
    for (int m = 0; m < 4; ++m)
#pragma unroll
      for (int n = 0; n < 4; ++n)
        acc[m][n] = __builtin_amdgcn_mfma_f32_16x16x32_bf16(af[m], bfr[n], acc[m][n], 0, 0, 0);
  };

  int cur = 0;
  STAGE_CONV(0, 0);
  __syncthreads();
  for (int t = 0; t < 72; ++t) {
    if (t < 71) STAGE_CONV(cur ^ 1, t + 1);
    else STAGE_ATTN(cur ^ 1, 0);
    COMPUTE(cur, accC);
    __syncthreads();
    cur ^= 1;
  }
  for (int t = 0; t < 8; ++t) {
    if (t < 7) STAGE_ATTN(cur ^ 1, t + 1);
    COMPUTE(cur, accY);
    __syncthreads();
    cur ^= 1;
  }

  float* ob = out + (long)b * CN;
  const float* cbb = cb + b * C;
#pragma unroll
  for (int m = 0; m < 4; ++m)
#pragma unroll
    for (int nn = 0; nn < 4; ++nn)
#pragma unroll
      for (int r = 0; r < 4; ++r) {
        int go = row0 + wm * 64 + m * 16 + kq * 4 + r;
        int cc = wn * 64 + nn * 16 + fr;
        int gn = col0 + cc;
        ob[(long)go * NTOK + gn] =
            accC[m][nn][r] + accY[m][nn][r] + conv_b[go] + cbb[jb + cc];
      }
}

// ---------------------------------------------------------------------------
extern "C" void kernel_launch(void* const* d_in, const int* in_sizes, int n_in,
                              void* d_out, int out_size, void* d_ws, size_t ws_size,
                              hipStream_t stream) {
  const float* x = (const float*)d_in[0];
  const float* qkv_w = (const float*)d_in[1];
  const float* qkv_b = (const float*)d_in[2];
  const float* proj_w = (const float*)d_in[3];
  const float* proj_b = (const float*)d_in[4];
  const float* conv_w = (const float*)d_in[5];
  const float* conv_b = (const float*)d_in[6];
  float* out = (float*)d_out;
  char* ws = (char*)d_ws;

  u16* xbf = (u16*)(ws);                    // 32 MB
  u16* xT = (u16*)(ws + 33554432);          // 32 MB
  u16* Gbf = (u16*)(ws + 67108864);         // 2 MB
  // union region: Gpart (16.7 MB, dead after reduceG) overlaps the small
  // intermediates created afterwards.
  float* Gpart = (float*)(ws + 69206016);
  u16* T1bf = (u16*)(ws + 69206016);
  float* Sf = (float*)(ws + 71303168);
  u16* attnT = (u16*)(ws + 75497472);
  u16* Mbf = (u16*)(ws + 77594624);
  u16* W2bf = (u16*)(ws + 79691776);
  u16* Wq = (u16*)(ws + 85983232);
  u16* Wk = (u16*)(ws + 86114304);
  u16* WvT = (u16*)(ws + 86245376);
  u16* Pw = (u16*)(ws + 86376448);
  u16* cw = (u16*)(ws + 86507520);
  float* rws = (float*)(ws + 87687168);
  float* uws = (float*)(ws + 87703552);
  float* wws = (float*)(ws + 87719936);
  float* cb = (float*)(ws + 87736320);
  u16* zbuf = (u16*)(ws + 87752704);

  prep_w_kernel<<<3328, 256, 0, stream>>>(qkv_w, proj_w, conv_w, Wq, Wk, WvT,
                                          Pw, cw, rws, zbuf);
  prep_x_kernel<<<dim3(128, 8, BATCH), 256, 0, stream>>>(x, xbf, xT, rws);
  bias_uw_kernel<<<BATCH, 512, 0, stream>>>(qkv_w, rws, uws, wws);

  // G = X*X^T per batch, split-K x4 -> f32 partials
  gemm_glds_kernel<0><<<dim3(4, 4, BATCH), 256, 0, stream>>>(
      xbf, xbf, Gpart, 1024, 4096, 4096, 256, 2, CN, CN, 65536,
      0.f, nullptr, nullptr, nullptr, nullptr, 0);
  reduceG_kernel<<<dim3(64, BATCH), 256, 0, stream>>>(Gpart, Gbf);

  // T1 = Wq * G  (G symmetric)
  gemm_glds_kernel<1><<<dim3(4, 1, BATCH), 256, 0, stream>>>(
      Wq, Gbf, T1bf, 256, 256, 256, 256, 2, 0, 65536, 65536,
      0.f, nullptr, nullptr, nullptr, nullptr, 0);
  // S = (T1 * Wk^T + bias terms) * scale
  gemm_glds_kernel<2><<<dim3(4, 1, BATCH), 256, 0, stream>>>(
      T1bf, Wk, Sf, 256, 256, 256, 256, 2, 65536, 0, 65536,
      0.0625f, qkv_b, qkv_b + 256, uws, wws, 256);

  softmax_kernel<<<BATCH * C, 256, 0, stream>>>(Sf, attnT);

  // M = Pw * attn   (B operand = attn^T)
  gemm_glds_kernel<1><<<dim3(4, 1, BATCH), 256, 0, stream>>>(
      Pw, attnT, Mbf, 256, 256, 256, 256, 2, 0, 65536, 65536,
      0.f, nullptr, nullptr, nullptr, nullptr, 0);
  cbias_kernel<<<BATCH, 256, 0, stream>>>(Mbf, qkv_b, proj_b, cb);
  // W2 = M * Wv     (B operand = WvT)
  gemm_glds_kernel<1><<<dim3(4, 1, BATCH), 256, 0, stream>>>(
      Mbf, WvT, W2bf, 256, 256, 256, 256, 2, 65536, 0, 65536,
      0.f, nullptr, nullptr, nullptr, nullptr, 0);

  // fused conv + attention-output, single store of out
  convattn_kernel<<<dim3(64, BATCH), 256, 0, stream>>>(xT, cw, W2bf, zbuf,
                                                       conv_b, cb, out);
}